// Round 21
// baseline (51.663 us; speedup 1.0000x reference)
//
#include <hip/hip_runtime.h>
#include <math.h>

#define NPRED 16384
#define NGT   32768
#define BETA  0.45f
#define GAMMA 0.45f

#define NGROUP 16                 // block-y groups == stored keys per pred
#define SPG    4                  // splits per nn block (looped)
#define GSPLIT (NGROUP * SPG)     // 64 total splits (512 rows each)
#define NTILE  (NGT / 32)         // 1024 32-row tiles (10-bit tile id)
#define TPS32  16                 // 32-row tiles per split
#define PB     256                // preds per nn block (4 waves x 4 groups x 16)
#define NN_BX  (NPRED / PB)       // 64 chunks
#define RESB   (NPRED / 8)        // 2048 rescan blocks (8 preds each)

typedef float f32x4 __attribute__((ext_vector_type(4)));
typedef short short8 __attribute__((ext_vector_type(8)));

__device__ __forceinline__ unsigned bf16h(float f) {          // RNE f32->bf16
    unsigned u = __float_as_uint(f);
    return (u + 0x7FFFu + ((u >> 16) & 1u)) >> 16;
}
__device__ __forceinline__ float bf16f(unsigned h) { return __uint_as_float(h << 16); }
__device__ __forceinline__ unsigned pk2(unsigned lo, unsigned hi) { return lo | (hi << 16); }

// ---------------------------------------------------------------------------
// nn (R21): switch 32x32x16 -> 16x16x32 MFMA. C/D = 4 regs (was 16): kills
// the hidden per-MFMA AGPR round-trip (16 accvgpr_write zero-init + 16
// accvgpr_read) that R19/R20 counters implicate (~61 issued VALU/MFMA vs ~17
// in source). K-slot plan (verified exact, absmax 0.0 since R10), zero-
// extended to K=32:
//   A row j (lanes 0-15, k0-7):  [xh,xh,xl,xl, yh,yh,yl,yl]
//           (lanes 16-31,k8-15): [zh,zh,zl,zl, g2h,g2l,0,0]
//           (lanes 32-63: alias lanes 0-31 — B is 0 there, product vanishes)
//   B col i (lanes 0-15):  [mxh,mxl,mxh,mxl, myh,myl,myh,myl]
//           (lanes 16-31): [mzh,mzl,mzh,mzl, 1,1,0,0]
//           (lanes 32-63): 0
// => acc[j][i] = g_j^2 - 2 p_i . g_j. Correct under ANY common k-octet
// permutation of A/B (both operands share the lane->k map; zeros kill the
// rest). C/D: col=lane&15 (pred), row=(l>>4)*4+reg (gt row) [m89].
// Per 32-row tile per group: 2 MFMAs -> 7 fmin + 1 and_or + 1 fold.
// Keys: (bits & 0xFFFFFC00) | tile10. NO atomics/fences (R15 lesson).
// ---------------------------------------------------------------------------
__global__ __launch_bounds__(256, 4) void nn_kernel(
    const float* __restrict__ pred,
    const float* __restrict__ gt,
    unsigned* __restrict__ packed2)
{
    __shared__ uint4 AF[32 * 32];                       // 32 subtiles x 32 lanes, 16 KB

    const int l  = threadIdx.x & 63;
    const int w  = threadIdx.x >> 6;
    const int by = blockIdx.y;
    const int wbase = blockIdx.x * PB + w * 64;         // 64 preds per wave

    // ---- four B fragments (16 preds each), built once per block
    const int lk = l >> 4;                              // k-octet selector
    short8 bv[4];
#pragma unroll
    for (int g = 0; g < 4; ++g) {
        const int pi = wbase + g * 16 + (l & 15);
        const float x = pred[pi * 6 + 0], y = pred[pi * 6 + 1], zc = pred[pi * 6 + 2];
        const float mx = -2.0f * x, my = -2.0f * y, mz = -2.0f * zc;
        const unsigned xh = bf16h(mx), yh = bf16h(my), zh = bf16h(mz);
        const unsigned xl = bf16h(mx - bf16f(xh)), yl = bf16h(my - bf16f(yh));
        const unsigned zl = bf16h(mz - bf16f(zh));
        uint4 b;
        if (lk == 0)      b = make_uint4(pk2(xh, xl), pk2(xh, xl), pk2(yh, yl), pk2(yh, yl));
        else if (lk == 1) b = make_uint4(pk2(zh, zl), pk2(zh, zl), 0x3F803F80u, 0u);
        else              b = make_uint4(0u, 0u, 0u, 0u);
        bv[g] = *(const short8*)&b;
    }
    const f32x4 zero = {0.f, 0.f, 0.f, 0.f};
    const unsigned kmask = 0xFFFFFC00u;

    float kmin0 = 1e30f, kmin1 = 1e30f, kmin2 = 1e30f, kmin3 = 1e30f;

#pragma unroll 1
    for (int u = 0; u < SPG; ++u) {
        const int sp = by * SPG + u;                    // global split 0..63

        __syncthreads();    // previous split's compute done before overwrite
        // ---- stage 512 rows as 16x16x32 A-fragments (2 rows/thread)
#pragma unroll
        for (int k = 0; k < 2; ++k) {
            const int lrow = threadIdx.x + k * 256;     // 0..511
            const int j = sp * 512 + lrow;
            const float x = gt[j * 6 + 0], y = gt[j * 6 + 1], z = gt[j * 6 + 2];
            const float g2 = fmaf(x, x, fmaf(y, y, z * z));
            const unsigned xh = bf16h(x),  yh = bf16h(y),  zh = bf16h(z),  gh = bf16h(g2);
            const unsigned xl = bf16h(x - bf16f(xh)), yl = bf16h(y - bf16f(yh));
            const unsigned zl = bf16h(z - bf16f(zh)), gl = bf16h(g2 - bf16f(gh));
            const int st = lrow >> 4, r = lrow & 15;
            AF[st * 32 + r]      = make_uint4(pk2(xh, xh), pk2(xl, xl), pk2(yh, yh), pk2(yl, yl));
            AF[st * 32 + 16 + r] = make_uint4(pk2(zh, zh), pk2(zl, zl), pk2(gh, gl), 0u);
        }
        __syncthreads();

        // ---- scan 16 32-row tiles (2 subtiles each)
#pragma unroll 2
        for (int t2 = 0; t2 < TPS32; ++t2) {
            const uint4 au0 = AF[(t2 * 2) * 32 + (l & 31)];
            const uint4 au1 = AF[(t2 * 2 + 1) * 32 + (l & 31)];
            const short8 av0 = *(const short8*)&au0;
            const short8 av1 = *(const short8*)&au1;
            const int gtile = sp * TPS32 + t2;          // 10-bit, wave-uniform

#define GROUP_STEP(KM, G)                                                      \
            {                                                                  \
                const f32x4 a0 = __builtin_amdgcn_mfma_f32_16x16x32_bf16(      \
                    av0, bv[G], zero, 0, 0, 0);                                \
                const f32x4 a1 = __builtin_amdgcn_mfma_f32_16x16x32_bf16(      \
                    av1, bv[G], zero, 0, 0, 0);                                \
                const float m0 = fminf(fminf(a0[0], a0[1]), fminf(a0[2], a0[3]));\
                const float m1 = fminf(fminf(a1[0], a1[1]), fminf(a1[2], a1[3]));\
                const float m  = fminf(m0, m1);                                \
                const unsigned kb = (__float_as_uint(m) & kmask) | (unsigned)gtile;\
                KM = fminf(KM, __uint_as_float(kb));                           \
            }
            GROUP_STEP(kmin0, 0)
            GROUP_STEP(kmin1, 1)
            GROUP_STEP(kmin2, 2)
            GROUP_STEP(kmin3, 3)
#undef GROUP_STEP
        }
    }

    // merge lanes p, p+16, p+32, p+48 (same pred col, complementary rows)
#pragma unroll
    for (int g = 0; g < 4; ++g) {
        float kv = (g == 0) ? kmin0 : (g == 1) ? kmin1 : (g == 2) ? kmin2 : kmin3;
        kv = fminf(kv, __shfl_xor(kv, 16, 64));
        kv = fminf(kv, __shfl_xor(kv, 32, 64));
        if (l < 16)
            packed2[(size_t)(wbase + g * 16 + l) * NGROUP + by] = __float_as_uint(kv);
    }
}

// ---------------------------------------------------------------------------
// rescan: 2048 blocks x 8 preds. Per pred: lanes 0-15 load the pred's 16
// group keys (64 B contiguous), fminf shuffle-reduce, tile = bits & 0x3FF;
// exact fp32 argmin in the winning 32-row tile (first occurrence; float2
// position loads); normals cosine; per-block partial. No atomics, no fences.
// ---------------------------------------------------------------------------
__global__ __launch_bounds__(256) void rescan_kernel(
    const float* __restrict__ pred,
    const float* __restrict__ gt,
    const unsigned* __restrict__ packed2,
    float* __restrict__ partials)
{
    __shared__ float part[8];
    const int w = threadIdx.x >> 6, l = threadIdx.x & 63;
    const int half = l >> 5, jl = l & 31;
    const int pi = blockIdx.x * 8 + w * 2 + half;

    const unsigned* kp = packed2 + (size_t)pi * NGROUP;
    float e = (jl < NGROUP) ? __uint_as_float(kp[jl]) : 1e30f;
#pragma unroll
    for (int off = 16; off; off >>= 1)
        e = fminf(e, __shfl_xor(e, off, 32));
    const unsigned tix = __float_as_uint(e) & 0x3FFu;   // winning 32-row tile

    const int row = (int)tix * 32 + jl;
    const float2* gr = (const float2*)(gt + row * 6);   // 24 B rows, 8 B aligned
    const float2 ga = gr[0], gb = gr[1];
    const float gx = ga.x, gy = ga.y, gz = gb.x;
    const float g2 = fmaf(gx, gx, fmaf(gy, gy, gz * gz));
    const float2* pr = (const float2*)(pred + pi * 6);
    const float2 pa = pr[0], pb = pr[1];
    const float px = pa.x, py = pa.y, pz = pb.x;
    float d = fmaf(px, -2.0f * gx, fmaf(py, -2.0f * gy, fmaf(pz, -2.0f * gz, g2)));
    int jj = jl;
#pragma unroll
    for (int off = 16; off; off >>= 1) {
        const float d2 = __shfl_xor(d, off, 32);
        const int   j2 = __shfl_xor(jj, off, 32);
        const bool t = (d2 < d) || (d2 == d && j2 < jj);
        d  = t ? d2 : d;
        jj = t ? j2 : jj;
    }
    if (jl == 0) {
        const int idx = (int)tix * 32 + jj;
        const float nx = pred[pi * 6 + 3], ny = pred[pi * 6 + 4], nz = pred[pi * 6 + 5];
        const float ax = gt[idx * 6 + 3],  ay = gt[idx * 6 + 4],  az = gt[idx * 6 + 5];
        const float pn = fmaxf(sqrtf(fmaf(nx, nx, fmaf(ny, ny, nz * nz))), 1e-12f);
        const float gn = fmaxf(sqrtf(fmaf(ax, ax, fmaf(ay, ay, az * az))), 1e-12f);
        part[w * 2 + half] = 1.0f - fmaf(nx, ax, fmaf(ny, ay, nz * az)) / (pn * gn);
    }
    __syncthreads();
    if (threadIdx.x == 0) {
        float s = 0.f;
#pragma unroll
        for (int i = 0; i < 8; ++i) s += part[i];
        partials[blockIdx.x] = s;
    }
}

// ---------------------------------------------------------------------------
// final: sum partials + regularizer, single write to out[0].
// ---------------------------------------------------------------------------
__global__ __launch_bounds__(256) void final_kernel(
    const float* __restrict__ partials,
    const float* __restrict__ Rm,
    const float* __restrict__ tv,
    const float* __restrict__ sv,
    float* __restrict__ out)
{
    __shared__ float ws_[4];
    float s = 0.f;
    for (int i = threadIdx.x; i < RESB; i += 256) s += partials[i];
#pragma unroll
    for (int off = 32; off; off >>= 1) s += __shfl_down(s, off, 64);
    if ((threadIdx.x & 63) == 0) ws_[threadIdx.x >> 6] = s;
    __syncthreads();
    if (threadIdx.x == 0) {
        const float t = ws_[0] + ws_[1] + ws_[2] + ws_[3];
        float rs = 0.f;
#pragma unroll
        for (int k = 0; k < 9; ++k) {
            const float v = Rm[k] - ((k % 4 == 0) ? 1.0f : 0.0f);
            rs = fmaf(v, v, rs);
        }
        const float rot = sqrtf(rs);
        const float tr  = sqrtf(fmaf(tv[0], tv[0], fmaf(tv[1], tv[1], tv[2] * tv[2])));
        const float sc  = (sv[0] - 1.0f) * (sv[0] - 1.0f);
        out[0] = GAMMA * t / (float)NPRED + BETA * (rot + tr + sc);
    }
}

extern "C" void kernel_launch(void* const* d_in, const int* in_sizes, int n_in,
                              void* d_out, int out_size, void* d_ws, size_t ws_size,
                              hipStream_t stream)
{
    const float* pred = (const float*)d_in[0];
    const float* gt   = (const float*)d_in[1];
    const float* Rm   = (const float*)d_in[2];
    const float* tv   = (const float*)d_in[3];
    const float* sv   = (const float*)d_in[4];
    float* out = (float*)d_out;

    unsigned* packed2 = (unsigned*)d_ws;                                  // 1 MB
    float* partials   = (float*)((char*)d_ws + (size_t)NPRED * NGROUP * 4);   // 8 KB

    nn_kernel<<<dim3(NN_BX, NGROUP), 256, 0, stream>>>(pred, gt, packed2);
    rescan_kernel<<<RESB, 256, 0, stream>>>(pred, gt, packed2, partials);
    final_kernel<<<1, 256, 0, stream>>>(partials, Rm, tv, sv, out);
}